// Round 7
// baseline (1632.818 us; speedup 1.0000x reference)
//
#include <hip/hip_runtime.h>
#include <hip/hip_bf16.h>

#define PCHUNK 2048
#define NBK 1024      // scan width; buckets of 128 nodes: 100000>>7 = 781 max
#define BSZ 128       // nodes per bucket
#define CAP 2560      // per-bucket edge capacity (mean 2046, +11 sigma)

__device__ inline float bf2f(unsigned int u16) { return __uint_as_float(u16 << 16); }
__device__ inline unsigned short f2bf(float f) {
    __hip_bfloat16 b = __float2bfloat16(f);
    return *(unsigned short*)&b;
}

typedef __attribute__((ext_vector_type(8))) short v8s;
typedef __attribute__((ext_vector_type(4))) float v4f;

// ---- phase 1: partition edges into 128-node dst-buckets; also zeroes pool ----
__global__ void k_partition(const int* __restrict__ src, const int* __restrict__ dst, int E,
                            int* __restrict__ bucket_cnt, unsigned int* __restrict__ buckets,
                            float* __restrict__ zero_base, int zero_count) {
    __shared__ int histA[NBK], histB[NBK];
    __shared__ int shiftb[NBK], cursor[NBK];
    __shared__ unsigned long long staged[PCHUNK];
    int t = threadIdx.x;
    int base = blockIdx.x * PCHUNK;
    for (int i = blockIdx.x * 256 + t; i < zero_count; i += gridDim.x * 256)
        zero_base[i] = 0.f;
    for (int i = t; i < NBK; i += 256) histA[i] = 0;
    __syncthreads();
    for (int i = t; i < PCHUNK; i += 256) {
        int e = base + i;
        if (e < E) atomicAdd(&histA[dst[e] >> 7], 1);
    }
    __syncthreads();
    int* pin = histA; int* pout = histB;
    for (int off = 1; off < NBK; off <<= 1) {
        for (int i = t; i < NBK; i += 256) {
            int v = pin[i];
            if (i >= off) v += pin[i - off];
            pout[i] = v;
        }
        __syncthreads();
        int* tmp = pin; pin = pout; pout = tmp;
    }
    for (int i = t; i < NBK; i += 256) {
        int excl = (i ? pin[i - 1] : 0);
        int cnt = pin[i] - excl;
        cursor[i] = excl;
        if (cnt > 0) {
            int g = atomicAdd(&bucket_cnt[i], cnt);
            shiftb[i] = g - excl;
        }
    }
    __syncthreads();
    for (int i = t; i < PCHUNK; i += 256) {
        int e = base + i;
        if (e < E) {
            int d = dst[e];
            int b = d >> 7;
            int r = atomicAdd(&cursor[b], 1);
            staged[r] = ((unsigned long long)b << 32) |
                        (unsigned int)(src[e] | ((d & (BSZ - 1)) << 24));
        }
    }
    __syncthreads();
    int tot = pin[NBK - 1];
    for (int i = t; i < tot; i += 256) {
        unsigned long long v = staged[i];
        int b = (int)(v >> 32);
        buckets[(size_t)b * CAP + shiftb[b] + i] = (unsigned int)v;
    }
}

// ---- per-bucket degree histogram -> dinv, fused xw1: A = bf16((x@W1)*dinv) ----
__global__ void k_deg_xw1(const unsigned int* __restrict__ buckets,
                          const int* __restrict__ bucket_cnt,
                          const float* __restrict__ x, const float* __restrict__ W1,
                          float* __restrict__ dinv, unsigned short* __restrict__ A, int N) {
    __shared__ int dl[BSZ];
    __shared__ float W1s[6 * 64];
    __shared__ float xs[BSZ * 6];
    int b = blockIdx.x, t = threadIdx.x;
    int nb0 = b * BSZ;
    for (int i = t; i < 6 * 64; i += 256) W1s[i] = W1[i];
    for (int i = t; i < BSZ * 6; i += 256) {
        int node = nb0 + i / 6;
        xs[i] = (node < N) ? x[(size_t)nb0 * 6 + i] : 0.f;
    }
    if (t < BSZ) dl[t] = 0;
    __syncthreads();
    int cnt = bucket_cnt[b];
    if (cnt > CAP) cnt = CAP;
    const unsigned int* bp = buckets + (size_t)b * CAP;
    for (int i = t; i < cnt; i += 256) atomicAdd(&dl[bp[i] >> 24], 1);
    __syncthreads();
    if (t < BSZ) {
        int n = nb0 + t;
        if (n < N) dinv[n] = rsqrtf((float)dl[t] + 1.0f);
    }
    int ch = t & 63, sub = t >> 6;
    for (int ii = 0; ii < BSZ / 4; ++ii) {
        int nl = ii * 4 + sub;
        int node = nb0 + nl;
        if (node < N) {
            float acc = 0.f;
            #pragma unroll
            for (int k = 0; k < 6; ++k) acc += xs[nl * 6 + k] * W1s[k * 64 + ch];
            float di = rsqrtf((float)dl[nl] + 1.0f);
            A[(size_t)node * 64 + ch] = f2bf(acc * di);
        }
    }
}

// ---- bucket pull: LDS accumulator over 128 nodes x 64 ch.
//      mode1 (pool==null): H = bf16(relu(dinv*(acc+self)+bias))
//      mode2: atomicAdd into pool[batch[n]] ----
__global__ void k_bucket_pull(const unsigned short* __restrict__ A,
                              const unsigned int* __restrict__ buckets,
                              const int* __restrict__ bucket_cnt,
                              const float* __restrict__ dinv,
                              const float* __restrict__ bias,
                              unsigned short* __restrict__ Hout,
                              const int* __restrict__ batch,
                              float* __restrict__ pool, int N) {
    __shared__ float acc[BSZ * 64];   // 32 KB
    int b = blockIdx.x, t = threadIdx.x;
    int wave = t >> 6, lane = t & 63;
    float4* a4 = (float4*)acc;
    for (int i = t; i < BSZ * 16; i += 256) a4[i] = make_float4(0.f, 0.f, 0.f, 0.f);
    __syncthreads();
    int cnt = bucket_cnt[b];
    if (cnt > CAP) cnt = CAP;
    const unsigned int* bp = buckets + (size_t)b * CAP;
    const unsigned int BAD = 0xFFFFFFFFu;
    for (int base = wave * 8; base < cnt; base += 32) {
        int ii = base + (lane & 7);
        unsigned int mine = (ii < cnt) ? bp[ii] : BAD;
        unsigned int e[8];
        float v[8];
        #pragma unroll
        for (int j = 0; j < 8; ++j) e[j] = __shfl(mine, j, 64);
        #pragma unroll
        for (int j = 0; j < 8; ++j) {
            unsigned int s = e[j] & 0x00FFFFFFu;
            if (s > (unsigned)(N - 1)) s = 0;
            v[j] = bf2f(A[((size_t)s << 6) + lane]);
        }
        #pragma unroll
        for (int j = 0; j < 8; ++j) {
            if (e[j] != BAD)
                atomicAdd(&acc[((e[j] >> 24) << 6) + lane], v[j]);
        }
    }
    __syncthreads();
    for (int nl = wave; nl < BSZ; nl += 4) {
        int n = b * BSZ + nl;
        if (n >= N) break;
        float self = bf2f(A[((size_t)n << 6) + lane]);
        float v = dinv[n] * (acc[(nl << 6) + lane] + self) + bias[lane];
        v = fmaxf(v, 0.f);
        if (pool) atomicAdd(&pool[((size_t)batch[n] << 6) + lane], v);
        else Hout[((size_t)n << 6) + lane] = f2bf(v);
    }
}

// xw2 via MFMA: A2 = bf16((H[N,64](bf16) @ W2[64,64]) * dinv), W2 split hi+lo bf16
__global__ void k_xw2_mfma(const unsigned short* __restrict__ H, const float* __restrict__ W2,
                           const float* __restrict__ dinv, unsigned short* __restrict__ A,
                           int N, int ntiles) {
    int t = threadIdx.x;
    int lane = t & 63;
    int cbase = (t >> 6) * 16;
    int q = lane >> 4, m = lane & 15;
    v8s b0h, b0l, b1h, b1l;
    #pragma unroll
    for (int j = 0; j < 8; ++j) {
        float w0 = W2[(q * 8 + j) * 64 + cbase + m];
        unsigned short h0 = f2bf(w0);
        b0h[j] = (short)h0;
        b0l[j] = (short)f2bf(w0 - bf2f(h0));
        float w1 = W2[(32 + q * 8 + j) * 64 + cbase + m];
        unsigned short h1 = f2bf(w1);
        b1h[j] = (short)h1;
        b1l[j] = (short)f2bf(w1 - bf2f(h1));
    }
    for (int tile = blockIdx.x; tile < ntiles; tile += gridDim.x) {
        int n0 = tile * 16;
        int nm = n0 + m; if (nm >= N) nm = N - 1;
        union { uint4 u; v8s s; } a0u, a1u;
        a0u.u = *(const uint4*)(H + ((size_t)nm << 6) + q * 8);
        a1u.u = *(const uint4*)(H + ((size_t)nm << 6) + 32 + q * 8);
        v4f acc = {0.f, 0.f, 0.f, 0.f};
        acc = __builtin_amdgcn_mfma_f32_16x16x32_bf16(a0u.s, b0l, acc, 0, 0, 0);
        acc = __builtin_amdgcn_mfma_f32_16x16x32_bf16(a1u.s, b1l, acc, 0, 0, 0);
        acc = __builtin_amdgcn_mfma_f32_16x16x32_bf16(a0u.s, b0h, acc, 0, 0, 0);
        acc = __builtin_amdgcn_mfma_f32_16x16x32_bf16(a1u.s, b1h, acc, 0, 0, 0);
        #pragma unroll
        for (int r = 0; r < 4; ++r) {
            int node = n0 + q * 4 + r;   // C/D: col=lane&15, row=(lane>>4)*4+r
            if (node < N)
                A[(size_t)node * 64 + cbase + m] = f2bf(acc[r] * dinv[node]);
        }
    }
}

// per-graph head; graph node-count via binary search on sorted batch
__global__ void k_final(const float* __restrict__ pool, const int* __restrict__ batch, int N,
                        const int* __restrict__ lig, const int* __restrict__ add,
                        const int* __restrict__ base, const int* __restrict__ aryl,
                        const float* __restrict__ e_lig, const float* __restrict__ e_add,
                        const float* __restrict__ e_base, const float* __restrict__ e_aryl,
                        const float* __restrict__ lin1W, const float* __restrict__ lin1b,
                        const float* __restrict__ lin2W, const float* __restrict__ lin2b,
                        float* __restrict__ out) {
    int g = blockIdx.x;
    int c = threadIdx.x;  // 64 threads = 1 wave
    __shared__ float cat[128];
    int res = 0;
    if (c < 2) {  // lanes 0,1: lower_bound(batch, g + c)
        int target = g + c;
        int lo = 0, hi = N;
        while (lo < hi) {
            int mid = (lo + hi) >> 1;
            if (batch[mid] < target) lo = mid + 1; else hi = mid;
        }
        res = lo;
    }
    int lo = __shfl(res, 0, 64), hi = __shfl(res, 1, 64);
    float invc = 1.0f / fmaxf((float)(hi - lo), 1.0f);
    cat[c] = pool[(size_t)g * 64 + c] * invc;
    float ev;
    if (c < 16)      ev = e_lig[lig[g] * 16 + c];
    else if (c < 32) ev = e_add[add[g] * 16 + (c - 16)];
    else if (c < 48) ev = e_base[base[g] * 16 + (c - 32)];
    else             ev = e_aryl[aryl[g] * 16 + (c - 48)];
    cat[64 + c] = ev;
    __syncthreads();
    float acc = lin1b[c];
    #pragma unroll
    for (int k = 0; k < 128; ++k) acc += cat[k] * lin1W[k * 64 + c];
    float p = fmaxf(acc, 0.f) * lin2W[c];
    #pragma unroll
    for (int off = 32; off > 0; off >>= 1) p += __shfl_down(p, off, 64);
    if (c == 0) out[g] = p + lin2b[0];
}

extern "C" void kernel_launch(void* const* d_in, const int* in_sizes, int n_in,
                              void* d_out, int out_size, void* d_ws, size_t ws_size,
                              hipStream_t stream) {
    const float* x      = (const float*)d_in[0];
    const int*   ei     = (const int*)d_in[1];
    const int*   batch  = (const int*)d_in[2];
    const int*   lig    = (const int*)d_in[3];
    const int*   addi   = (const int*)d_in[4];
    const int*   basei  = (const int*)d_in[5];
    const int*   aryl   = (const int*)d_in[6];
    const float* e_lig  = (const float*)d_in[7];
    const float* e_add  = (const float*)d_in[8];
    const float* e_base = (const float*)d_in[9];
    const float* e_aryl = (const float*)d_in[10];
    const float* W1     = (const float*)d_in[11];
    const float* b1     = (const float*)d_in[12];
    const float* W2     = (const float*)d_in[13];
    const float* b2     = (const float*)d_in[14];
    const float* lin1W  = (const float*)d_in[15];
    const float* lin1b  = (const float*)d_in[16];
    const float* lin2W  = (const float*)d_in[17];
    const float* lin2b  = (const float*)d_in[18];
    float* out = (float*)d_out;

    const int N = in_sizes[0] / 6;
    const int E = in_sizes[1] / 2;
    const int G = in_sizes[3];
    const int* src = ei;
    const int* dst = ei + E;
    const int NBb = (N + BSZ - 1) / BSZ;   // 782 buckets

    // ---- workspace layout ----
    char* w = (char*)d_ws;
    size_t SA = (size_t)N * 64;
    unsigned short* A = (unsigned short*)w;  w += SA * 2;   // Abar (bf16)
    unsigned short* H = (unsigned short*)w;  w += SA * 2;   // h1 (bf16)
    float* dinv = (float*)w;   w += (size_t)N * 4;
    float* pool = (float*)w;   w += (size_t)G * 64 * 4;     // zeroed by k_partition
    int* bucket_cnt = (int*)w; w += NBK * 4;                // zeroed by memset
    unsigned int* buckets = (unsigned int*)w;  w += (size_t)NBb * CAP * 4;

    hipMemsetAsync(bucket_cnt, 0, NBK * 4, stream);

    const int npart = (E + PCHUNK - 1) / PCHUNK;
    k_partition<<<npart, 256, 0, stream>>>(src, dst, E, bucket_cnt, buckets,
                                           pool, G * 64);
    k_deg_xw1<<<NBb, 256, 0, stream>>>(buckets, bucket_cnt, x, W1, dinv, A, N);

    // conv1
    k_bucket_pull<<<NBb, 256, 0, stream>>>(A, buckets, bucket_cnt, dinv, b1,
                                           H, nullptr, nullptr, N);
    // xw2 (MFMA)
    const int ntiles = (N + 15) / 16;
    k_xw2_mfma<<<640, 256, 0, stream>>>(H, W2, dinv, A, N, ntiles);

    // conv2 + fused pooling
    k_bucket_pull<<<NBb, 256, 0, stream>>>(A, buckets, bucket_cnt, dinv, b2,
                                           nullptr, batch, pool, N);

    // head
    k_final<<<G, 64, 0, stream>>>(pool, batch, N, lig, addi, basei, aryl,
                                  e_lig, e_add, e_base, e_aryl,
                                  lin1W, lin1b, lin2W, lin2b, out);
}

// Round 8
// 330.372 us; speedup vs baseline: 4.9424x; 4.9424x over previous
//
#include <hip/hip_runtime.h>
#include <hip/hip_bf16.h>

#define PCHUNK 4096
#define NBK 1024      // hist width (padded); used buckets = ceil(100000/128) = 782
#define BSZ 128       // nodes per bucket
#define CAP 2560      // per-bucket edge capacity (mean 2046, +11 sigma)

__device__ inline float bf2f(unsigned int u16) { return __uint_as_float(u16 << 16); }
__device__ inline unsigned short f2bf(float f) {
    __hip_bfloat16 b = __float2bfloat16(f);
    return *(unsigned short*)&b;
}

typedef __attribute__((ext_vector_type(8))) short v8s;
typedef __attribute__((ext_vector_type(4))) float v4f;

// ---- phase 1: partition edges into 128-node dst-buckets; also zeroes pool ----
__global__ void k_partition(const int* __restrict__ src, const int* __restrict__ dst, int E,
                            int* __restrict__ bucket_cnt, unsigned int* __restrict__ buckets,
                            float* __restrict__ zero_base, int zero_count) {
    __shared__ int hist[NBK];
    __shared__ int shift[NBK];
    __shared__ int cursor[NBK];
    __shared__ unsigned int staged_e[PCHUNK];
    __shared__ unsigned short staged_b[PCHUNK];
    __shared__ int wtot[4];
    int t = threadIdx.x;
    int lane = t & 63, wave = t >> 6;
    int base = blockIdx.x * PCHUNK;
    for (int i = blockIdx.x * 256 + t; i < zero_count; i += gridDim.x * 256)
        zero_base[i] = 0.f;
    for (int i = t; i < NBK; i += 256) hist[i] = 0;
    __syncthreads();
    int nE = E - base; if (nE > PCHUNK) nE = PCHUNK;
    for (int i = t; i < nE; i += 256) atomicAdd(&hist[dst[base + i] >> 7], 1);
    __syncthreads();
    // wave-shfl scan over NBK entries: thread t owns hist[4t..4t+3]
    int h0 = hist[4 * t], h1 = hist[4 * t + 1], h2 = hist[4 * t + 2], h3 = hist[4 * t + 3];
    int p1 = h0 + h1, p2 = p1 + h2, s = p2 + h3;
    int si = s;
    #pragma unroll
    for (int off = 1; off < 64; off <<= 1) {
        int u = __shfl_up(si, off, 64);
        if (lane >= off) si += u;
    }
    if (lane == 63) wtot[wave] = si;
    __syncthreads();
    int woff = 0;
    #pragma unroll
    for (int w2 = 0; w2 < 4; ++w2) woff += (w2 < wave) ? wtot[w2] : 0;
    int ebase = woff + si - s;
    int ex[4] = {ebase, ebase + h0, ebase + p1, ebase + p2};
    int cn[4] = {h0, h1, h2, h3};
    #pragma unroll
    for (int j = 0; j < 4; ++j) {
        int bidx = 4 * t + j;
        cursor[bidx] = ex[j];
        if (cn[j] > 0) {
            int g = atomicAdd(&bucket_cnt[bidx], cn[j]);
            shift[bidx] = g - ex[j];
        }
    }
    __syncthreads();
    for (int i = t; i < nE; i += 256) {
        int d = dst[base + i];
        int b = d >> 7;
        int r = atomicAdd(&cursor[b], 1);
        staged_e[r] = (unsigned int)src[base + i] | ((unsigned int)(d & (BSZ - 1)) << 24);
        staged_b[r] = (unsigned short)b;
    }
    __syncthreads();
    for (int i = t; i < nE; i += 256) {
        int b = staged_b[i];
        buckets[(size_t)b * CAP + shift[b] + i] = staged_e[i];
    }
}

// ---- phase 2: per-bucket CSR build (wave-scan, direct scatter store),
//      emits deg/offs/dinv, then fused xw1: A = bf16((x@W1)*dinv) ----
__global__ void k_bucket_csr_xw1(const unsigned int* __restrict__ buckets,
                                 const int* __restrict__ bucket_cnt,
                                 int* __restrict__ offs, int* __restrict__ deg,
                                 float* __restrict__ dinv, int* __restrict__ csr,
                                 const float* __restrict__ x, const float* __restrict__ W1,
                                 unsigned short* __restrict__ A, int N) {
    __shared__ int dl[BSZ], cur[BSZ];
    __shared__ float dis[BSZ];
    __shared__ float W1s[6 * 64];
    __shared__ float xs[BSZ * 6];
    __shared__ int w0tot;
    int b = blockIdx.x, t = threadIdx.x;
    int nb0 = b * BSZ;
    for (int i = t; i < 6 * 64; i += 256) W1s[i] = W1[i];
    for (int i = t; i < BSZ * 6; i += 256) {
        int node = nb0 + i / 6;
        xs[i] = (node < N) ? x[(size_t)nb0 * 6 + i] : 0.f;
    }
    if (t < BSZ) dl[t] = 0;
    __syncthreads();
    int cnt = bucket_cnt[b];
    if (cnt > CAP) cnt = CAP;
    const unsigned int* bp = buckets + (size_t)b * CAP;
    for (int i = t; i < cnt; i += 256) atomicAdd(&dl[bp[i] >> 24], 1);
    __syncthreads();
    // 128-wide scan via 2 wave-shfl scans (all threads execute; t>=128 inert)
    int lane = t & 63, wave = t >> 6;
    int v = (t < BSZ) ? dl[t] : 0;
    int si = v;
    #pragma unroll
    for (int off = 1; off < 64; off <<= 1) {
        int u = __shfl_up(si, off, 64);
        if (lane >= off) si += u;
    }
    if (t == 63) w0tot = si;
    __syncthreads();
    int ex = si - v + ((wave == 1) ? w0tot : 0);
    if (t < BSZ) {
        cur[t] = ex;
        float di = rsqrtf((float)v + 1.0f);
        dis[t] = di;
        int n = nb0 + t;
        if (n < N) { offs[n] = b * CAP + ex; deg[n] = v; dinv[n] = di; }
    }
    __syncthreads();
    int* cg = csr + (size_t)b * CAP;
    for (int i = t; i < cnt; i += 256) {
        unsigned int e = bp[i];
        int r = atomicAdd(&cur[e >> 24], 1);
        cg[r] = (int)(e & 0x00FFFFFFu);
    }
    // ---- fused xw1 for this block's 128 nodes ----
    int ch = t & 63, sub = t >> 6;
    for (int nl = sub; nl < BSZ; nl += 4) {
        int node = nb0 + nl;
        if (node < N) {
            float acc = 0.f;
            #pragma unroll
            for (int k = 0; k < 6; ++k) acc += xs[nl * 6 + k] * W1s[k * 64 + ch];
            A[(size_t)node * 64 + ch] = f2bf(acc * dis[nl]);
        }
    }
}

// pull conv1: h[n] = relu(dinv[n]*(sum Abar[s] + Abar[n]) + b), stored bf16
__global__ void k_pull(const unsigned short* __restrict__ A, const int* __restrict__ csr,
                       const int* __restrict__ offs, const int* __restrict__ deg,
                       const float* __restrict__ dinv, const float* __restrict__ bias,
                       unsigned short* __restrict__ H, int N) {
    int tid = threadIdx.x;
    int n = blockIdx.x * 4 + (tid >> 6);
    int lane = tid & 63;
    if (n >= N) return;
    int base = offs[n], dg = deg[n];
    float acc = bf2f(A[((size_t)n << 6) + lane]);
    int i = 0;
    for (; i + 8 <= dg; i += 8) {
        int s0 = csr[base + i],     s1 = csr[base + i + 1];
        int s2 = csr[base + i + 2], s3 = csr[base + i + 3];
        int s4 = csr[base + i + 4], s5 = csr[base + i + 5];
        int s6 = csr[base + i + 6], s7 = csr[base + i + 7];
        float a0 = bf2f(A[((size_t)s0 << 6) + lane]);
        float a1 = bf2f(A[((size_t)s1 << 6) + lane]);
        float a2 = bf2f(A[((size_t)s2 << 6) + lane]);
        float a3 = bf2f(A[((size_t)s3 << 6) + lane]);
        float a4 = bf2f(A[((size_t)s4 << 6) + lane]);
        float a5 = bf2f(A[((size_t)s5 << 6) + lane]);
        float a6 = bf2f(A[((size_t)s6 << 6) + lane]);
        float a7 = bf2f(A[((size_t)s7 << 6) + lane]);
        acc += ((a0 + a1) + (a2 + a3)) + ((a4 + a5) + (a6 + a7));
    }
    for (; i < dg; ++i) acc += bf2f(A[((size_t)csr[base + i] << 6) + lane]);
    float v = fmaxf(dinv[n] * acc + bias[lane], 0.f);
    H[((size_t)n << 6) + lane] = f2bf(v);
}

// xw2 via MFMA: A2 = bf16((H[N,64](bf16) @ W2[64,64]) * dinv), W2 split hi+lo bf16
__global__ void k_xw2_mfma(const unsigned short* __restrict__ H, const float* __restrict__ W2,
                           const float* __restrict__ dinv, unsigned short* __restrict__ A,
                           int N, int ntiles) {
    int t = threadIdx.x;
    int lane = t & 63;
    int cbase = (t >> 6) * 16;
    int q = lane >> 4, m = lane & 15;
    v8s b0h, b0l, b1h, b1l;
    #pragma unroll
    for (int j = 0; j < 8; ++j) {
        float w0 = W2[(q * 8 + j) * 64 + cbase + m];
        unsigned short h0 = f2bf(w0);
        b0h[j] = (short)h0;
        b0l[j] = (short)f2bf(w0 - bf2f(h0));
        float w1 = W2[(32 + q * 8 + j) * 64 + cbase + m];
        unsigned short h1 = f2bf(w1);
        b1h[j] = (short)h1;
        b1l[j] = (short)f2bf(w1 - bf2f(h1));
    }
    for (int tile = blockIdx.x; tile < ntiles; tile += gridDim.x) {
        int n0 = tile * 16;
        int nm = n0 + m; if (nm >= N) nm = N - 1;
        union { uint4 u; v8s s; } a0u, a1u;
        a0u.u = *(const uint4*)(H + ((size_t)nm << 6) + q * 8);
        a1u.u = *(const uint4*)(H + ((size_t)nm << 6) + 32 + q * 8);
        v4f acc = {0.f, 0.f, 0.f, 0.f};
        acc = __builtin_amdgcn_mfma_f32_16x16x32_bf16(a0u.s, b0l, acc, 0, 0, 0);
        acc = __builtin_amdgcn_mfma_f32_16x16x32_bf16(a1u.s, b1l, acc, 0, 0, 0);
        acc = __builtin_amdgcn_mfma_f32_16x16x32_bf16(a0u.s, b0h, acc, 0, 0, 0);
        acc = __builtin_amdgcn_mfma_f32_16x16x32_bf16(a1u.s, b1h, acc, 0, 0, 0);
        #pragma unroll
        for (int r = 0; r < 4; ++r) {
            int node = n0 + q * 4 + r;   // C/D: col=lane&15, row=(lane>>4)*4+r
            if (node < N)
                A[(size_t)node * 64 + cbase + m] = f2bf(acc[r] * dinv[node]);
        }
    }
}

// pull conv2 fused with mean-pool accumulation (full-wave contiguous atomics)
__global__ void k_pull_pool(const unsigned short* __restrict__ A, const int* __restrict__ csr,
                            const int* __restrict__ offs, const int* __restrict__ deg,
                            const float* __restrict__ dinv, const float* __restrict__ bias,
                            const int* __restrict__ batch, float* __restrict__ pool, int N) {
    int tid = threadIdx.x;
    int n = blockIdx.x * 4 + (tid >> 6);
    int lane = tid & 63;
    if (n >= N) return;
    int base = offs[n], dg = deg[n];
    float acc = bf2f(A[((size_t)n << 6) + lane]);
    int i = 0;
    for (; i + 8 <= dg; i += 8) {
        int s0 = csr[base + i],     s1 = csr[base + i + 1];
        int s2 = csr[base + i + 2], s3 = csr[base + i + 3];
        int s4 = csr[base + i + 4], s5 = csr[base + i + 5];
        int s6 = csr[base + i + 6], s7 = csr[base + i + 7];
        float a0 = bf2f(A[((size_t)s0 << 6) + lane]);
        float a1 = bf2f(A[((size_t)s1 << 6) + lane]);
        float a2 = bf2f(A[((size_t)s2 << 6) + lane]);
        float a3 = bf2f(A[((size_t)s3 << 6) + lane]);
        float a4 = bf2f(A[((size_t)s4 << 6) + lane]);
        float a5 = bf2f(A[((size_t)s5 << 6) + lane]);
        float a6 = bf2f(A[((size_t)s6 << 6) + lane]);
        float a7 = bf2f(A[((size_t)s7 << 6) + lane]);
        acc += ((a0 + a1) + (a2 + a3)) + ((a4 + a5) + (a6 + a7));
    }
    for (; i < dg; ++i) acc += bf2f(A[((size_t)csr[base + i] << 6) + lane]);
    float v = fmaxf(dinv[n] * acc + bias[lane], 0.f);
    atomicAdd(&pool[(size_t)batch[n] * 64 + lane], v);
}

// per-graph head; graph node-count via binary search on sorted batch
__global__ void k_final(const float* __restrict__ pool, const int* __restrict__ batch, int N,
                        const int* __restrict__ lig, const int* __restrict__ add,
                        const int* __restrict__ base, const int* __restrict__ aryl,
                        const float* __restrict__ e_lig, const float* __restrict__ e_add,
                        const float* __restrict__ e_base, const float* __restrict__ e_aryl,
                        const float* __restrict__ lin1W, const float* __restrict__ lin1b,
                        const float* __restrict__ lin2W, const float* __restrict__ lin2b,
                        float* __restrict__ out) {
    int g = blockIdx.x;
    int c = threadIdx.x;  // 64 threads = 1 wave
    __shared__ float cat[128];
    int res = 0;
    if (c < 2) {  // lanes 0,1: lower_bound(batch, g + c)
        int target = g + c;
        int lo = 0, hi = N;
        while (lo < hi) {
            int mid = (lo + hi) >> 1;
            if (batch[mid] < target) lo = mid + 1; else hi = mid;
        }
        res = lo;
    }
    int lo = __shfl(res, 0, 64), hi = __shfl(res, 1, 64);
    float invc = 1.0f / fmaxf((float)(hi - lo), 1.0f);
    cat[c] = pool[(size_t)g * 64 + c] * invc;
    float ev;
    if (c < 16)      ev = e_lig[lig[g] * 16 + c];
    else if (c < 32) ev = e_add[add[g] * 16 + (c - 16)];
    else if (c < 48) ev = e_base[base[g] * 16 + (c - 32)];
    else             ev = e_aryl[aryl[g] * 16 + (c - 48)];
    cat[64 + c] = ev;
    __syncthreads();
    float acc = lin1b[c];
    #pragma unroll
    for (int k = 0; k < 128; ++k) acc += cat[k] * lin1W[k * 64 + c];
    float p = fmaxf(acc, 0.f) * lin2W[c];
    #pragma unroll
    for (int off = 32; off > 0; off >>= 1) p += __shfl_down(p, off, 64);
    if (c == 0) out[g] = p + lin2b[0];
}

extern "C" void kernel_launch(void* const* d_in, const int* in_sizes, int n_in,
                              void* d_out, int out_size, void* d_ws, size_t ws_size,
                              hipStream_t stream) {
    const float* x      = (const float*)d_in[0];
    const int*   ei     = (const int*)d_in[1];
    const int*   batch  = (const int*)d_in[2];
    const int*   lig    = (const int*)d_in[3];
    const int*   addi   = (const int*)d_in[4];
    const int*   basei  = (const int*)d_in[5];
    const int*   aryl   = (const int*)d_in[6];
    const float* e_lig  = (const float*)d_in[7];
    const float* e_add  = (const float*)d_in[8];
    const float* e_base = (const float*)d_in[9];
    const float* e_aryl = (const float*)d_in[10];
    const float* W1     = (const float*)d_in[11];
    const float* b1     = (const float*)d_in[12];
    const float* W2     = (const float*)d_in[13];
    const float* b2     = (const float*)d_in[14];
    const float* lin1W  = (const float*)d_in[15];
    const float* lin1b  = (const float*)d_in[16];
    const float* lin2W  = (const float*)d_in[17];
    const float* lin2b  = (const float*)d_in[18];
    float* out = (float*)d_out;

    const int N = in_sizes[0] / 6;
    const int E = in_sizes[1] / 2;
    const int G = in_sizes[3];
    const int* src = ei;
    const int* dst = ei + E;
    const int NBb = (N + BSZ - 1) / BSZ;   // 782 buckets

    // ---- workspace layout ----
    char* w = (char*)d_ws;
    size_t SA = (size_t)N * 64;
    unsigned short* A = (unsigned short*)w;  w += SA * 2;   // Abar (bf16)
    unsigned short* H = (unsigned short*)w;  w += SA * 2;   // h1 (bf16)
    float* dinv = (float*)w;   w += (size_t)N * 4;
    int*   deg  = (int*)w;     w += (size_t)N * 4;
    int*   offs = (int*)w;     w += (size_t)N * 4;
    float* pool = (float*)w;   w += (size_t)G * 64 * 4;     // zeroed by k_partition
    int* bucket_cnt = (int*)w; w += NBK * 4;                // zeroed by memset
    unsigned int* buckets = (unsigned int*)w;  w += (size_t)NBb * CAP * 4;
    int* csr    = (int*)w;     w += (size_t)NBb * CAP * 4;

    hipMemsetAsync(bucket_cnt, 0, NBK * 4, stream);

    const int npart = (E + PCHUNK - 1) / PCHUNK;   // 391 blocks
    k_partition<<<npart, 256, 0, stream>>>(src, dst, E, bucket_cnt, buckets,
                                           pool, G * 64);
    k_bucket_csr_xw1<<<NBb, 256, 0, stream>>>(buckets, bucket_cnt,
                                              offs, deg, dinv, csr, x, W1, A, N);

    // conv1
    k_pull<<<(N + 3) / 4, 256, 0, stream>>>(A, csr, offs, deg, dinv, b1, H, N);

    // xw2 (MFMA)
    const int ntiles = (N + 15) / 16;
    k_xw2_mfma<<<640, 256, 0, stream>>>(H, W2, dinv, A, N, ntiles);

    // conv2 + fused pooling
    k_pull_pool<<<(N + 3) / 4, 256, 0, stream>>>(A, csr, offs, deg, dinv, b2, batch, pool, N);

    // head
    k_final<<<G, 64, 0, stream>>>(pool, batch, N, lig, addi, basei, aryl,
                                  e_lig, e_add, e_base, e_aryl,
                                  lin1W, lin1b, lin2W, lin2b, out);
}

// Round 9
// 319.209 us; speedup vs baseline: 5.1152x; 1.0350x over previous
//
#include <hip/hip_runtime.h>
#include <hip/hip_bf16.h>

#define PCHUNK 4096
#define NBK 1024      // hist width (padded); used buckets = ceil(100000/128) = 782
#define BSZ 128       // nodes per bucket
#define CAP 2560      // per-bucket edge capacity (mean 2046, +11 sigma)

__device__ inline float bf2f(unsigned int u16) { return __uint_as_float(u16 << 16); }
__device__ inline unsigned short f2bf(float f) {
    __hip_bfloat16 b = __float2bfloat16(f);
    return *(unsigned short*)&b;
}

typedef __attribute__((ext_vector_type(8))) short v8s;
typedef __attribute__((ext_vector_type(4))) float v4f;

// ---- phase 1: partition edges into 128-node dst-buckets; also zeroes pool ----
__global__ void k_partition(const int* __restrict__ src, const int* __restrict__ dst, int E,
                            int* __restrict__ bucket_cnt, unsigned int* __restrict__ buckets,
                            float* __restrict__ zero_base, int zero_count) {
    __shared__ int hist[NBK];
    __shared__ int shift[NBK];
    __shared__ int cursor[NBK];
    __shared__ unsigned int staged_e[PCHUNK];
    __shared__ unsigned short staged_b[PCHUNK];
    __shared__ int wtot[4];
    int t = threadIdx.x;
    int lane = t & 63, wave = t >> 6;
    int base = blockIdx.x * PCHUNK;
    for (int i = blockIdx.x * 256 + t; i < zero_count; i += gridDim.x * 256)
        zero_base[i] = 0.f;
    for (int i = t; i < NBK; i += 256) hist[i] = 0;
    __syncthreads();
    int nE = E - base; if (nE > PCHUNK) nE = PCHUNK;
    for (int i = t; i < nE; i += 256) atomicAdd(&hist[dst[base + i] >> 7], 1);
    __syncthreads();
    // wave-shfl scan over NBK entries: thread t owns hist[4t..4t+3]
    int h0 = hist[4 * t], h1 = hist[4 * t + 1], h2 = hist[4 * t + 2], h3 = hist[4 * t + 3];
    int p1 = h0 + h1, p2 = p1 + h2, s = p2 + h3;
    int si = s;
    #pragma unroll
    for (int off = 1; off < 64; off <<= 1) {
        int u = __shfl_up(si, off, 64);
        if (lane >= off) si += u;
    }
    if (lane == 63) wtot[wave] = si;
    __syncthreads();
    int woff = 0;
    #pragma unroll
    for (int w2 = 0; w2 < 4; ++w2) woff += (w2 < wave) ? wtot[w2] : 0;
    int ebase = woff + si - s;
    int ex[4] = {ebase, ebase + h0, ebase + p1, ebase + p2};
    int cn[4] = {h0, h1, h2, h3};
    #pragma unroll
    for (int j = 0; j < 4; ++j) {
        int bidx = 4 * t + j;
        cursor[bidx] = ex[j];
        if (cn[j] > 0) {
            int g = atomicAdd(&bucket_cnt[bidx], cn[j]);
            shift[bidx] = g - ex[j];
        }
    }
    __syncthreads();
    for (int i = t; i < nE; i += 256) {
        int d = dst[base + i];
        int b = d >> 7;
        int r = atomicAdd(&cursor[b], 1);
        staged_e[r] = (unsigned int)src[base + i] | ((unsigned int)(d & (BSZ - 1)) << 24);
        staged_b[r] = (unsigned short)b;
    }
    __syncthreads();
    for (int i = t; i < nE; i += 256) {
        int b = staged_b[i];
        buckets[(size_t)b * CAP + shift[b] + i] = staged_e[i];
    }
}

// ---- phase 2: per-bucket CSR build (wave-scan, direct scatter store),
//      emits deg/offs/dinv, then fused xw1: A = bf16((x@W1)*dinv) ----
__global__ void k_bucket_csr_xw1(const unsigned int* __restrict__ buckets,
                                 const int* __restrict__ bucket_cnt,
                                 int* __restrict__ offs, int* __restrict__ deg,
                                 float* __restrict__ dinv, int* __restrict__ csr,
                                 const float* __restrict__ x, const float* __restrict__ W1,
                                 unsigned short* __restrict__ A, int N) {
    __shared__ int dl[BSZ], cur[BSZ];
    __shared__ float dis[BSZ];
    __shared__ float W1s[6 * 64];
    __shared__ float xs[BSZ * 6];
    __shared__ int w0tot;
    int b = blockIdx.x, t = threadIdx.x;
    int nb0 = b * BSZ;
    for (int i = t; i < 6 * 64; i += 256) W1s[i] = W1[i];
    for (int i = t; i < BSZ * 6; i += 256) {
        int node = nb0 + i / 6;
        xs[i] = (node < N) ? x[(size_t)nb0 * 6 + i] : 0.f;
    }
    if (t < BSZ) dl[t] = 0;
    __syncthreads();
    int cnt = bucket_cnt[b];
    if (cnt > CAP) cnt = CAP;
    const unsigned int* bp = buckets + (size_t)b * CAP;
    for (int i = t; i < cnt; i += 256) atomicAdd(&dl[bp[i] >> 24], 1);
    __syncthreads();
    int lane = t & 63, wave = t >> 6;
    int v = (t < BSZ) ? dl[t] : 0;
    int si = v;
    #pragma unroll
    for (int off = 1; off < 64; off <<= 1) {
        int u = __shfl_up(si, off, 64);
        if (lane >= off) si += u;
    }
    if (t == 63) w0tot = si;
    __syncthreads();
    int ex = si - v + ((wave == 1) ? w0tot : 0);
    if (t < BSZ) {
        cur[t] = ex;
        float di = rsqrtf((float)v + 1.0f);
        dis[t] = di;
        int n = nb0 + t;
        if (n < N) { offs[n] = b * CAP + ex; deg[n] = v; dinv[n] = di; }
    }
    __syncthreads();
    int* cg = csr + (size_t)b * CAP;
    for (int i = t; i < cnt; i += 256) {
        unsigned int e = bp[i];
        int r = atomicAdd(&cur[e >> 24], 1);
        cg[r] = (int)(e & 0x00FFFFFFu);
    }
    int ch = t & 63, sub = t >> 6;
    for (int nl = sub; nl < BSZ; nl += 4) {
        int node = nb0 + nl;
        if (node < N) {
            float acc = 0.f;
            #pragma unroll
            for (int k = 0; k < 6; ++k) acc += xs[nl * 6 + k] * W1s[k * 64 + ch];
            A[(size_t)node * 64 + ch] = f2bf(acc * dis[nl]);
        }
    }
}

// ---- pull conv1 fused with xw2 MFMA: block owns 16 consecutive nodes.
//      Each wave pulls 4 nodes (h1 = relu(...) -> LDS bf16 tile), then the
//      block computes A2 = bf16((Htile @ W2) * dinv) via hi/lo-split MFMA. ----
__global__ void k_pull1_xw2(const unsigned short* __restrict__ A, const int* __restrict__ csr,
                            const int* __restrict__ offs, const int* __restrict__ deg,
                            const float* __restrict__ dinv, const float* __restrict__ bias,
                            const float* __restrict__ W2, unsigned short* __restrict__ A2,
                            int N) {
    __shared__ unsigned short Ht[16][72];   // +8 pad: breaks 16-way bank aliasing
    int t = threadIdx.x;
    int lane = t & 63, wave = t >> 6;
    int q = lane >> 4, m = lane & 15;
    int cbase = wave * 16;
    // W2 B-fragments (hi/lo bf16 split), same mapping as verified R6 kernel
    v8s b0h, b0l, b1h, b1l;
    #pragma unroll
    for (int j = 0; j < 8; ++j) {
        float w0 = W2[(q * 8 + j) * 64 + cbase + m];
        unsigned short h0 = f2bf(w0);
        b0h[j] = (short)h0;
        b0l[j] = (short)f2bf(w0 - bf2f(h0));
        float w1 = W2[(32 + q * 8 + j) * 64 + cbase + m];
        unsigned short h1 = f2bf(w1);
        b1h[j] = (short)h1;
        b1l[j] = (short)f2bf(w1 - bf2f(h1));
    }
    int n0 = blockIdx.x * 16;
    float bias_l = bias[lane];
    for (int r = 0; r < 4; ++r) {
        int nl = wave * 4 + r;
        int n = n0 + nl;
        if (n < N) {
            int base = offs[n], dg = deg[n];
            float acc = bf2f(A[((size_t)n << 6) + lane]);
            int i = 0;
            for (; i + 8 <= dg; i += 8) {
                int s0 = csr[base + i],     s1 = csr[base + i + 1];
                int s2 = csr[base + i + 2], s3 = csr[base + i + 3];
                int s4 = csr[base + i + 4], s5 = csr[base + i + 5];
                int s6 = csr[base + i + 6], s7 = csr[base + i + 7];
                float a0 = bf2f(A[((size_t)s0 << 6) + lane]);
                float a1 = bf2f(A[((size_t)s1 << 6) + lane]);
                float a2 = bf2f(A[((size_t)s2 << 6) + lane]);
                float a3 = bf2f(A[((size_t)s3 << 6) + lane]);
                float a4 = bf2f(A[((size_t)s4 << 6) + lane]);
                float a5 = bf2f(A[((size_t)s5 << 6) + lane]);
                float a6 = bf2f(A[((size_t)s6 << 6) + lane]);
                float a7 = bf2f(A[((size_t)s7 << 6) + lane]);
                acc += ((a0 + a1) + (a2 + a3)) + ((a4 + a5) + (a6 + a7));
            }
            for (; i < dg; ++i) acc += bf2f(A[((size_t)csr[base + i] << 6) + lane]);
            float v = fmaxf(dinv[n] * acc + bias_l, 0.f);
            Ht[nl][lane] = f2bf(v);
        }
    }
    __syncthreads();
    // MFMA phase: A-frag row m from LDS tile, K split 0..31 / 32..63
    union { uint4 u; v8s s; } a0u, a1u;
    a0u.u = *(const uint4*)&Ht[m][q * 8];
    a1u.u = *(const uint4*)&Ht[m][32 + q * 8];
    v4f acc = {0.f, 0.f, 0.f, 0.f};
    acc = __builtin_amdgcn_mfma_f32_16x16x32_bf16(a0u.s, b0l, acc, 0, 0, 0);
    acc = __builtin_amdgcn_mfma_f32_16x16x32_bf16(a1u.s, b1l, acc, 0, 0, 0);
    acc = __builtin_amdgcn_mfma_f32_16x16x32_bf16(a0u.s, b0h, acc, 0, 0, 0);
    acc = __builtin_amdgcn_mfma_f32_16x16x32_bf16(a1u.s, b1h, acc, 0, 0, 0);
    #pragma unroll
    for (int r = 0; r < 4; ++r) {
        int node = n0 + q * 4 + r;   // C/D: col=lane&15, row=(lane>>4)*4+r
        if (node < N)
            A2[(size_t)node * 64 + cbase + m] = f2bf(acc[r] * dinv[node]);
    }
}

// pull conv2 fused with mean-pool accumulation; 16-deep gather batches
__global__ void k_pull_pool(const unsigned short* __restrict__ A, const int* __restrict__ csr,
                            const int* __restrict__ offs, const int* __restrict__ deg,
                            const float* __restrict__ dinv, const float* __restrict__ bias,
                            const int* __restrict__ batch, float* __restrict__ pool, int N) {
    int tid = threadIdx.x;
    int n = blockIdx.x * 4 + (tid >> 6);
    int lane = tid & 63;
    if (n >= N) return;
    int base = offs[n], dg = deg[n];
    float acc = bf2f(A[((size_t)n << 6) + lane]);
    int i = 0;
    for (; i + 16 <= dg; i += 16) {
        int s[16];
        #pragma unroll
        for (int j = 0; j < 16; ++j) s[j] = csr[base + i + j];
        float a[16];
        #pragma unroll
        for (int j = 0; j < 16; ++j) a[j] = bf2f(A[((size_t)s[j] << 6) + lane]);
        float t0 = ((a[0] + a[1]) + (a[2] + a[3])) + ((a[4] + a[5]) + (a[6] + a[7]));
        float t1 = ((a[8] + a[9]) + (a[10] + a[11])) + ((a[12] + a[13]) + (a[14] + a[15]));
        acc += t0 + t1;
    }
    for (; i + 8 <= dg; i += 8) {
        int s0 = csr[base + i],     s1 = csr[base + i + 1];
        int s2 = csr[base + i + 2], s3 = csr[base + i + 3];
        int s4 = csr[base + i + 4], s5 = csr[base + i + 5];
        int s6 = csr[base + i + 6], s7 = csr[base + i + 7];
        float a0 = bf2f(A[((size_t)s0 << 6) + lane]);
        float a1 = bf2f(A[((size_t)s1 << 6) + lane]);
        float a2 = bf2f(A[((size_t)s2 << 6) + lane]);
        float a3 = bf2f(A[((size_t)s3 << 6) + lane]);
        float a4 = bf2f(A[((size_t)s4 << 6) + lane]);
        float a5 = bf2f(A[((size_t)s5 << 6) + lane]);
        float a6 = bf2f(A[((size_t)s6 << 6) + lane]);
        float a7 = bf2f(A[((size_t)s7 << 6) + lane]);
        acc += ((a0 + a1) + (a2 + a3)) + ((a4 + a5) + (a6 + a7));
    }
    for (; i < dg; ++i) acc += bf2f(A[((size_t)csr[base + i] << 6) + lane]);
    float v = fmaxf(dinv[n] * acc + bias[lane], 0.f);
    atomicAdd(&pool[(size_t)batch[n] * 64 + lane], v);
}

// per-graph head; graph node-count via binary search on sorted batch
__global__ void k_final(const float* __restrict__ pool, const int* __restrict__ batch, int N,
                        const int* __restrict__ lig, const int* __restrict__ add,
                        const int* __restrict__ base, const int* __restrict__ aryl,
                        const float* __restrict__ e_lig, const float* __restrict__ e_add,
                        const float* __restrict__ e_base, const float* __restrict__ e_aryl,
                        const float* __restrict__ lin1W, const float* __restrict__ lin1b,
                        const float* __restrict__ lin2W, const float* __restrict__ lin2b,
                        float* __restrict__ out) {
    int g = blockIdx.x;
    int c = threadIdx.x;  // 64 threads = 1 wave
    __shared__ float cat[128];
    int res = 0;
    if (c < 2) {  // lanes 0,1: lower_bound(batch, g + c)
        int target = g + c;
        int lo = 0, hi = N;
        while (lo < hi) {
            int mid = (lo + hi) >> 1;
            if (batch[mid] < target) lo = mid + 1; else hi = mid;
        }
        res = lo;
    }
    int lo = __shfl(res, 0, 64), hi = __shfl(res, 1, 64);
    float invc = 1.0f / fmaxf((float)(hi - lo), 1.0f);
    cat[c] = pool[(size_t)g * 64 + c] * invc;
    float ev;
    if (c < 16)      ev = e_lig[lig[g] * 16 + c];
    else if (c < 32) ev = e_add[add[g] * 16 + (c - 16)];
    else if (c < 48) ev = e_base[base[g] * 16 + (c - 32)];
    else             ev = e_aryl[aryl[g] * 16 + (c - 48)];
    cat[64 + c] = ev;
    __syncthreads();
    float acc = lin1b[c];
    #pragma unroll
    for (int k = 0; k < 128; ++k) acc += cat[k] * lin1W[k * 64 + c];
    float p = fmaxf(acc, 0.f) * lin2W[c];
    #pragma unroll
    for (int off = 32; off > 0; off >>= 1) p += __shfl_down(p, off, 64);
    if (c == 0) out[g] = p + lin2b[0];
}

extern "C" void kernel_launch(void* const* d_in, const int* in_sizes, int n_in,
                              void* d_out, int out_size, void* d_ws, size_t ws_size,
                              hipStream_t stream) {
    const float* x      = (const float*)d_in[0];
    const int*   ei     = (const int*)d_in[1];
    const int*   batch  = (const int*)d_in[2];
    const int*   lig    = (const int*)d_in[3];
    const int*   addi   = (const int*)d_in[4];
    const int*   basei  = (const int*)d_in[5];
    const int*   aryl   = (const int*)d_in[6];
    const float* e_lig  = (const float*)d_in[7];
    const float* e_add  = (const float*)d_in[8];
    const float* e_base = (const float*)d_in[9];
    const float* e_aryl = (const float*)d_in[10];
    const float* W1     = (const float*)d_in[11];
    const float* b1     = (const float*)d_in[12];
    const float* W2     = (const float*)d_in[13];
    const float* b2     = (const float*)d_in[14];
    const float* lin1W  = (const float*)d_in[15];
    const float* lin1b  = (const float*)d_in[16];
    const float* lin2W  = (const float*)d_in[17];
    const float* lin2b  = (const float*)d_in[18];
    float* out = (float*)d_out;

    const int N = in_sizes[0] / 6;
    const int E = in_sizes[1] / 2;
    const int G = in_sizes[3];
    const int* src = ei;
    const int* dst = ei + E;
    const int NBb = (N + BSZ - 1) / BSZ;   // 782 buckets

    // ---- workspace layout ----
    char* w = (char*)d_ws;
    size_t SA = (size_t)N * 64;
    unsigned short* A  = (unsigned short*)w;  w += SA * 2;  // Abar conv1 (bf16)
    unsigned short* A2 = (unsigned short*)w;  w += SA * 2;  // Abar conv2 (bf16)
    float* dinv = (float*)w;   w += (size_t)N * 4;
    int*   deg  = (int*)w;     w += (size_t)N * 4;
    int*   offs = (int*)w;     w += (size_t)N * 4;
    float* pool = (float*)w;   w += (size_t)G * 64 * 4;     // zeroed by k_partition
    int* bucket_cnt = (int*)w; w += NBK * 4;                // zeroed by memset
    unsigned int* buckets = (unsigned int*)w;  w += (size_t)NBb * CAP * 4;
    int* csr    = (int*)w;     w += (size_t)NBb * CAP * 4;

    hipMemsetAsync(bucket_cnt, 0, NBK * 4, stream);

    const int npart = (E + PCHUNK - 1) / PCHUNK;   // 391 blocks
    k_partition<<<npart, 256, 0, stream>>>(src, dst, E, bucket_cnt, buckets,
                                           pool, G * 64);
    k_bucket_csr_xw1<<<NBb, 256, 0, stream>>>(buckets, bucket_cnt,
                                              offs, deg, dinv, csr, x, W1, A, N);

    // conv1 pull + fused xw2 MFMA
    k_pull1_xw2<<<(N + 15) / 16, 256, 0, stream>>>(A, csr, offs, deg, dinv, b1, W2, A2, N);

    // conv2 + fused pooling
    k_pull_pool<<<(N + 3) / 4, 256, 0, stream>>>(A2, csr, offs, deg, dinv, b2, batch, pool, N);

    // head
    k_final<<<G, 64, 0, stream>>>(pool, batch, N, lig, addi, basei, aryl,
                                  e_lig, e_add, e_base, e_aryl,
                                  lin1W, lin1b, lin2W, lin2b, out);
}